// Round 1
// baseline (2725.679 us; speedup 1.0000x reference)
//
#include <hip/hip_runtime.h>

#define DD 128
#define PP 15
#define NNODES 10000
#define NEDGES 160000

typedef __attribute__((ext_vector_type(8))) short bf16x8;
typedef __attribute__((ext_vector_type(4))) float f32x4;

__device__ inline ushort f2bf(float f) {
  unsigned u = __builtin_bit_cast(unsigned, f);
  u += 0x7FFFu + ((u >> 16) & 1u);   // round-to-nearest-even
  return (ushort)(u >> 16);
}

__device__ inline f32x4 mfma16(bf16x8 a, bf16x8 b, f32x4 c) {
  return __builtin_amdgcn_mfma_f32_16x16x32_bf16(a, b, c, 0, 0, 0);
}

// Pack fp32 weight [P][K][128] into bf16 MFMA B-fragment order:
// out[p][cb][kt][lane][e] = w[p][kt*32 + (lane>>4)*8 + e][cb*16 + (lane&15)]
__global__ __launch_bounds__(256) void pack_w(const float* __restrict__ w,
                                              ushort* __restrict__ out,
                                              int K, int total) {
  int i = blockIdx.x * 256 + threadIdx.x;
  if (i >= total) return;
  int per = K * 128;
  int p = i / per, j = i % per;
  int e = j & 7;
  int lane = (j >> 3) & 63;
  int t = j >> 9;               // cb*nkt + kt
  int nkt = K >> 5;
  int kt = t % nkt, cb = t / nkt;
  int k = kt * 32 + ((lane >> 4) << 3) + e;
  int n = (cb << 4) + (lane & 15);
  out[i] = f2bf(w[(size_t)p * per + (size_t)k * 128 + n]);
}

// ---------------- edge kernel: 64 edges x 128 out per block, 4 waves ----------------
__global__ __launch_bounds__(256) void edge_kernel(
    const float* __restrict__ nbuf, float* __restrict__ ebuf,
    const int* __restrict__ srcI, const int* __restrict__ dstI,
    const ushort* __restrict__ w0, const float* __restrict__ b0,
    const ushort* __restrict__ w1, const float* __restrict__ b1,
    const ushort* __restrict__ w2, const float* __restrict__ b2,
    float* __restrict__ agg) {
  __shared__ ushort Alds[64 * 384];   // cat tile, bf16, 16B-slot XOR swizzled
  __shared__ ushort Hlds[64 * 128];   // hidden tile
  __shared__ int slds[64], dlds[64];

  const int tid = threadIdx.x;
  const int e0 = blockIdx.x * 64;
  const int lane = tid & 63, wv = tid >> 6;
  const int l15 = lane & 15, l4 = lane >> 4;

  if (tid < 64) slds[tid] = srcI[e0 + tid];
  else if (tid < 128) dlds[tid - 64] = dstI[e0 + tid - 64];
  __syncthreads();

  // stage cat = [n[src] | n[dst] | e] as bf16 into Alds (row stride 384, swizzled)
#pragma unroll
  for (int i = 0; i < 24; ++i) {
    int c = i * 256 + tid;
    int row = c / 96, f4 = c % 96;
    const float* sp;
    if (f4 < 32)       sp = nbuf + (size_t)slds[row] * DD + f4 * 4;
    else if (f4 < 64)  sp = nbuf + (size_t)dlds[row] * DD + (f4 - 32) * 4;
    else               sp = ebuf + (size_t)(e0 + row) * DD + (f4 - 64) * 4;
    float4 v = *(const float4*)sp;
    ushort4 hv;
    hv.x = f2bf(v.x); hv.y = f2bf(v.y); hv.z = f2bf(v.z); hv.w = f2bf(v.w);
    int slot = (f4 >> 1) ^ (row & 15);
    *(ushort4*)&Alds[row * 384 + slot * 8 + (f4 & 1) * 4] = hv;
  }
  __syncthreads();

  const f32x4 z = {0.f, 0.f, 0.f, 0.f};
  const int cbA = wv * 2, cbB = wv * 2 + 1;

  // ---- GEMM1: [64x384] @ w0[384x128] ----
  f32x4 acc[4][2];
#pragma unroll
  for (int rb = 0; rb < 4; ++rb) { acc[rb][0] = z; acc[rb][1] = z; }
#pragma unroll
  for (int kt = 0; kt < 12; ++kt) {
    bf16x8 bA = *(const bf16x8*)(w0 + (size_t)((cbA * 12 + kt) * 64 + lane) * 8);
    bf16x8 bB = *(const bf16x8*)(w0 + (size_t)((cbB * 12 + kt) * 64 + lane) * 8);
#pragma unroll
    for (int rb = 0; rb < 4; ++rb) {
      int row = rb * 16 + l15;
      bf16x8 a = *(const bf16x8*)&Alds[row * 384 + (((kt * 4 + l4) ^ (row & 15)) * 8)];
      acc[rb][0] = mfma16(a, bA, acc[rb][0]);
      acc[rb][1] = mfma16(a, bB, acc[rb][1]);
    }
  }
  // h1 = relu(acc + b0) -> Hlds
  {
    float biasA = b0[cbA * 16 + l15], biasB = b0[cbB * 16 + l15];
#pragma unroll
    for (int cbi = 0; cbi < 2; ++cbi) {
      int col = (wv * 2 + cbi) * 16 + l15;
      float bias = cbi ? biasB : biasA;
#pragma unroll
      for (int rb = 0; rb < 4; ++rb)
#pragma unroll
        for (int r = 0; r < 4; ++r) {
          int row = rb * 16 + l4 * 4 + r;
          float v = fmaxf(acc[rb][cbi][r] + bias, 0.f);
          Hlds[row * 128 + (((col >> 3) ^ (row & 15)) * 8) + (col & 7)] = f2bf(v);
        }
    }
  }
  __syncthreads();

  // ---- GEMM2: [64x128] @ w1[128x128] ----
#pragma unroll
  for (int rb = 0; rb < 4; ++rb) { acc[rb][0] = z; acc[rb][1] = z; }
#pragma unroll
  for (int kt = 0; kt < 4; ++kt) {
    bf16x8 bA = *(const bf16x8*)(w1 + (size_t)((cbA * 4 + kt) * 64 + lane) * 8);
    bf16x8 bB = *(const bf16x8*)(w1 + (size_t)((cbB * 4 + kt) * 64 + lane) * 8);
#pragma unroll
    for (int rb = 0; rb < 4; ++rb) {
      int row = rb * 16 + l15;
      bf16x8 a = *(const bf16x8*)&Hlds[row * 128 + (((kt * 4 + l4) ^ (row & 15)) * 8)];
      acc[rb][0] = mfma16(a, bA, acc[rb][0]);
      acc[rb][1] = mfma16(a, bB, acc[rb][1]);
    }
  }
  __syncthreads();   // all reads of Hlds done
  {
    float biasA = b1[cbA * 16 + l15], biasB = b1[cbB * 16 + l15];
#pragma unroll
    for (int cbi = 0; cbi < 2; ++cbi) {
      int col = (wv * 2 + cbi) * 16 + l15;
      float bias = cbi ? biasB : biasA;
#pragma unroll
      for (int rb = 0; rb < 4; ++rb)
#pragma unroll
        for (int r = 0; r < 4; ++r) {
          int row = rb * 16 + l4 * 4 + r;
          float v = fmaxf(acc[rb][cbi][r] + bias, 0.f);
          Hlds[row * 128 + (((col >> 3) ^ (row & 15)) * 8) + (col & 7)] = f2bf(v);
        }
    }
  }
  __syncthreads();

  // ---- GEMM3: [64x128] @ w2[128x128], + b2 + residual, store + scatter ----
#pragma unroll
  for (int rb = 0; rb < 4; ++rb) { acc[rb][0] = z; acc[rb][1] = z; }
#pragma unroll
  for (int kt = 0; kt < 4; ++kt) {
    bf16x8 bA = *(const bf16x8*)(w2 + (size_t)((cbA * 4 + kt) * 64 + lane) * 8);
    bf16x8 bB = *(const bf16x8*)(w2 + (size_t)((cbB * 4 + kt) * 64 + lane) * 8);
#pragma unroll
    for (int rb = 0; rb < 4; ++rb) {
      int row = rb * 16 + l15;
      bf16x8 a = *(const bf16x8*)&Hlds[row * 128 + (((kt * 4 + l4) ^ (row & 15)) * 8)];
      acc[rb][0] = mfma16(a, bA, acc[rb][0]);
      acc[rb][1] = mfma16(a, bB, acc[rb][1]);
    }
  }
  {
#pragma unroll
    for (int cbi = 0; cbi < 2; ++cbi) {
      int col = (wv * 2 + cbi) * 16 + l15;
      float bias = b2[col];
#pragma unroll
      for (int rb = 0; rb < 4; ++rb)
#pragma unroll
        for (int r = 0; r < 4; ++r) {
          int row = rb * 16 + l4 * 4 + r;
          size_t off = (size_t)(e0 + row) * DD + col;
          float res = ebuf[off] + acc[rb][cbi][r] + bias;
          ebuf[off] = res;
          atomicAdd(agg + (size_t)dlds[row] * DD + col, res);
        }
    }
  }
}

// ---------------- node kernel: 64 nodes x 128 out per block ----------------
__global__ __launch_bounds__(256) void node_kernel(
    float* __restrict__ nbuf, const float* __restrict__ agg,
    const ushort* __restrict__ w0, const float* __restrict__ b0,
    const ushort* __restrict__ w1, const float* __restrict__ b1,
    const ushort* __restrict__ w2, const float* __restrict__ b2) {
  __shared__ ushort Alds[64 * 256];
  __shared__ ushort Hlds[64 * 128];

  const int tid = threadIdx.x;
  const int n0 = blockIdx.x * 64;
  const int lane = tid & 63, wv = tid >> 6;
  const int l15 = lane & 15, l4 = lane >> 4;

  // stage cat_n = [n | agg]
#pragma unroll
  for (int i = 0; i < 16; ++i) {
    int c = i * 256 + tid;
    int row = c / 64, f4 = c % 64;
    int node = n0 + row;
    float4 v;
    if (node < NNODES) {
      const float* sp = (f4 < 32) ? (nbuf + (size_t)node * DD + f4 * 4)
                                  : (agg + (size_t)node * DD + (f4 - 32) * 4);
      v = *(const float4*)sp;
    } else {
      v.x = v.y = v.z = v.w = 0.f;
    }
    ushort4 hv;
    hv.x = f2bf(v.x); hv.y = f2bf(v.y); hv.z = f2bf(v.z); hv.w = f2bf(v.w);
    int slot = (f4 >> 1) ^ (row & 15);
    *(ushort4*)&Alds[row * 256 + slot * 8 + (f4 & 1) * 4] = hv;
  }
  __syncthreads();

  const f32x4 z = {0.f, 0.f, 0.f, 0.f};
  const int cbA = wv * 2, cbB = wv * 2 + 1;

  // ---- GEMM1: [64x256] @ nw0[256x128] ----
  f32x4 acc[4][2];
#pragma unroll
  for (int rb = 0; rb < 4; ++rb) { acc[rb][0] = z; acc[rb][1] = z; }
#pragma unroll
  for (int kt = 0; kt < 8; ++kt) {
    bf16x8 bA = *(const bf16x8*)(w0 + (size_t)((cbA * 8 + kt) * 64 + lane) * 8);
    bf16x8 bB = *(const bf16x8*)(w0 + (size_t)((cbB * 8 + kt) * 64 + lane) * 8);
#pragma unroll
    for (int rb = 0; rb < 4; ++rb) {
      int row = rb * 16 + l15;
      bf16x8 a = *(const bf16x8*)&Alds[row * 256 + (((kt * 4 + l4) ^ (row & 15)) * 8)];
      acc[rb][0] = mfma16(a, bA, acc[rb][0]);
      acc[rb][1] = mfma16(a, bB, acc[rb][1]);
    }
  }
  {
    float biasA = b0[cbA * 16 + l15], biasB = b0[cbB * 16 + l15];
#pragma unroll
    for (int cbi = 0; cbi < 2; ++cbi) {
      int col = (wv * 2 + cbi) * 16 + l15;
      float bias = cbi ? biasB : biasA;
#pragma unroll
      for (int rb = 0; rb < 4; ++rb)
#pragma unroll
        for (int r = 0; r < 4; ++r) {
          int row = rb * 16 + l4 * 4 + r;
          float v = fmaxf(acc[rb][cbi][r] + bias, 0.f);
          Hlds[row * 128 + (((col >> 3) ^ (row & 15)) * 8) + (col & 7)] = f2bf(v);
        }
    }
  }
  __syncthreads();

  // ---- GEMM2 ----
#pragma unroll
  for (int rb = 0; rb < 4; ++rb) { acc[rb][0] = z; acc[rb][1] = z; }
#pragma unroll
  for (int kt = 0; kt < 4; ++kt) {
    bf16x8 bA = *(const bf16x8*)(w1 + (size_t)((cbA * 4 + kt) * 64 + lane) * 8);
    bf16x8 bB = *(const bf16x8*)(w1 + (size_t)((cbB * 4 + kt) * 64 + lane) * 8);
#pragma unroll
    for (int rb = 0; rb < 4; ++rb) {
      int row = rb * 16 + l15;
      bf16x8 a = *(const bf16x8*)&Hlds[row * 128 + (((kt * 4 + l4) ^ (row & 15)) * 8)];
      acc[rb][0] = mfma16(a, bA, acc[rb][0]);
      acc[rb][1] = mfma16(a, bB, acc[rb][1]);
    }
  }
  __syncthreads();
  {
    float biasA = b1[cbA * 16 + l15], biasB = b1[cbB * 16 + l15];
#pragma unroll
    for (int cbi = 0; cbi < 2; ++cbi) {
      int col = (wv * 2 + cbi) * 16 + l15;
      float bias = cbi ? biasB : biasA;
#pragma unroll
      for (int rb = 0; rb < 4; ++rb)
#pragma unroll
        for (int r = 0; r < 4; ++r) {
          int row = rb * 16 + l4 * 4 + r;
          float v = fmaxf(acc[rb][cbi][r] + bias, 0.f);
          Hlds[row * 128 + (((col >> 3) ^ (row & 15)) * 8) + (col & 7)] = f2bf(v);
        }
    }
  }
  __syncthreads();

  // ---- GEMM3 + residual ----
#pragma unroll
  for (int rb = 0; rb < 4; ++rb) { acc[rb][0] = z; acc[rb][1] = z; }
#pragma unroll
  for (int kt = 0; kt < 4; ++kt) {
    bf16x8 bA = *(const bf16x8*)(w2 + (size_t)((cbA * 4 + kt) * 64 + lane) * 8);
    bf16x8 bB = *(const bf16x8*)(w2 + (size_t)((cbB * 4 + kt) * 64 + lane) * 8);
#pragma unroll
    for (int rb = 0; rb < 4; ++rb) {
      int row = rb * 16 + l15;
      bf16x8 a = *(const bf16x8*)&Hlds[row * 128 + (((kt * 4 + l4) ^ (row & 15)) * 8)];
      acc[rb][0] = mfma16(a, bA, acc[rb][0]);
      acc[rb][1] = mfma16(a, bB, acc[rb][1]);
    }
  }
  {
#pragma unroll
    for (int cbi = 0; cbi < 2; ++cbi) {
      int col = (wv * 2 + cbi) * 16 + l15;
      float bias = b2[col];
#pragma unroll
      for (int rb = 0; rb < 4; ++rb)
#pragma unroll
        for (int r = 0; r < 4; ++r) {
          int row = rb * 16 + l4 * 4 + r;
          int node = n0 + row;
          if (node < NNODES) {
            size_t off = (size_t)node * DD + col;
            nbuf[off] = nbuf[off] + acc[rb][cbi][r] + bias;
          }
        }
    }
  }
}

extern "C" void kernel_launch(void* const* d_in, const int* in_sizes, int n_in,
                              void* d_out, int out_size, void* d_ws, size_t ws_size,
                              hipStream_t stream) {
  const float* node_f = (const float*)d_in[0];
  const float* edge_f = (const float*)d_in[1];
  const int* srcI = (const int*)d_in[2];
  const int* dstI = (const int*)d_in[3];
  const float* ew0 = (const float*)d_in[4];
  const float* eb0 = (const float*)d_in[5];
  const float* ew1 = (const float*)d_in[6];
  const float* eb1 = (const float*)d_in[7];
  const float* ew2 = (const float*)d_in[8];
  const float* eb2 = (const float*)d_in[9];
  const float* nw0 = (const float*)d_in[10];
  const float* nb0 = (const float*)d_in[11];
  const float* nw1 = (const float*)d_in[12];
  const float* nb1 = (const float*)d_in[13];
  const float* nw2 = (const float*)d_in[14];
  const float* nb2 = (const float*)d_in[15];

  char* ws = (char*)d_ws;
  const size_t EB = (size_t)NEDGES * DD * 4;   // 81,920,000
  const size_t NB = (size_t)NNODES * DD * 4;   //  5,120,000
  float* ebuf = (float*)ws;
  float* nbuf = (float*)(ws + EB);
  float* agg  = (float*)(ws + EB + NB);
  ushort* pw  = (ushort*)(ws + EB + 2 * NB);
  ushort* pew0 = pw;                    // 15*384*128
  ushort* pew1 = pew0 + 737280;         // 15*128*128
  ushort* pew2 = pew1 + 245760;
  ushort* pnw0 = pew2 + 245760;         // 15*256*128
  ushort* pnw1 = pnw0 + 491520;
  ushort* pnw2 = pnw1 + 245760;

  // pack all weights to bf16 fragment layout
  {
    struct { const float* s; ushort* d; int K; } packs[6] = {
      {ew0, pew0, 384}, {ew1, pew1, 128}, {ew2, pew2, 128},
      {nw0, pnw0, 256}, {nw1, pnw1, 128}, {nw2, pnw2, 128},
    };
    for (int i = 0; i < 6; ++i) {
      int total = PP * packs[i].K * 128;
      pack_w<<<(total + 255) / 256, 256, 0, stream>>>(packs[i].s, packs[i].d,
                                                      packs[i].K, total);
    }
  }

  hipMemcpyAsync(ebuf, edge_f, EB, hipMemcpyDeviceToDevice, stream);
  hipMemcpyAsync(nbuf, node_f, NB, hipMemcpyDeviceToDevice, stream);

  const int eblocks = NEDGES / 64;                 // 2500
  const int nblocks = (NNODES + 63) / 64;          // 157

  for (int p = 0; p < PP; ++p) {
    hipMemsetAsync(agg, 0, NB, stream);
    edge_kernel<<<eblocks, 256, 0, stream>>>(
        nbuf, ebuf, srcI, dstI,
        pew0 + (size_t)p * 49152, eb0 + (size_t)p * DD,
        pew1 + (size_t)p * 16384, eb1 + (size_t)p * DD,
        pew2 + (size_t)p * 16384, eb2 + (size_t)p * DD, agg);
    node_kernel<<<nblocks, 256, 0, stream>>>(
        nbuf, agg,
        pnw0 + (size_t)p * 32768, nb0 + (size_t)p * DD,
        pnw1 + (size_t)p * 16384, nb1 + (size_t)p * DD,
        pnw2 + (size_t)p * 16384, nb2 + (size_t)p * DD);
  }

  hipMemcpyAsync(d_out, nbuf, NB, hipMemcpyDeviceToDevice, stream);
}